// Round 7
// baseline (882.967 us; speedup 1.0000x reference)
//
#include <hip/hip_runtime.h>

#define NP 22
#define NH 64
#define NL 5
#define NE 21

constexpr float CRc    = 3.0f;   // 15/L
constexpr float LOG2Mc = 7.0f;
constexpr float L2E    = 1.442695041f;

typedef __fp16 h2_t  __attribute__((ext_vector_type(2)));
typedef __fp16 f16x8 __attribute__((ext_vector_type(8)));
typedef float  f32x16 __attribute__((ext_vector_type(16)));

// ---- native single-instruction transcendentals
__device__ __forceinline__ float rcp_(float x) {
#if __has_builtin(__builtin_amdgcn_rcpf)
  return __builtin_amdgcn_rcpf(x);
#else
  float r; asm("v_rcp_f32 %0, %1" : "=v"(r) : "v"(x)); return r;
#endif
}
__device__ __forceinline__ float exp2_(float x) {
#if __has_builtin(__builtin_amdgcn_exp2f)
  return __builtin_amdgcn_exp2f(x);
#else
  float r; asm("v_exp_f32 %0, %1" : "=v"(r) : "v"(x)); return r;
#endif
}
__device__ __forceinline__ float sqrt_(float x) {
#if __has_builtin(__builtin_amdgcn_sqrtf)
  return __builtin_amdgcn_sqrtf(x);
#else
  float r; asm("v_sqrt_f32 %0, %1" : "=v"(r) : "v"(x)); return r;
#endif
}
__device__ __forceinline__ float sigf(float s)  { return rcp_(1.0f + exp2_(-L2E * s)); }
__device__ __forceinline__ float siluf(float s) { return s * sigf(s); }

__device__ __forceinline__ float rl_f(float v, int lane) {
  return __builtin_bit_cast(float, __builtin_amdgcn_readlane(__builtin_bit_cast(int, v), lane));
}
__device__ __forceinline__ h2_t rl_h2(h2_t v, int lane) {
  return __builtin_bit_cast(h2_t, __builtin_amdgcn_readlane(__builtin_bit_cast(int, v), lane));
}
__device__ __forceinline__ h2_t pkf(float a, float b) {
  return __builtin_amdgcn_cvt_pkrtz(a, b);
}
template <int CTRL>
__device__ __forceinline__ float dppmov(float v) {
  return __builtin_bit_cast(float,
      __builtin_amdgcn_update_dpp(0, __builtin_bit_cast(int, v), CTRL, 0xF, 0xF, true));
}
// sum over each 32-lane group
__device__ __forceinline__ float red32(float v) {
  v += dppmov<0xB1>(v);
  v += dppmov<0x4E>(v);
  v += dppmov<0x124>(v);
  v += dppmov<0x128>(v);
  v += __builtin_bit_cast(float, __builtin_amdgcn_ds_swizzle(
         __builtin_bit_cast(int, v), 0x401F));
  return v;
}
__device__ __forceinline__ float fdot2(h2_t a, h2_t b, float c) {
#if __has_builtin(__builtin_amdgcn_fdot2)
  return __builtin_amdgcn_fdot2(a, b, c, false);
#else
  float d;
  asm("v_dot2_f32_f16 %0, %1, %2, %3"
      : "=v"(d)
      : "v"(__builtin_bit_cast(int, a)), "v"(__builtin_bit_cast(int, b)), "v"(c));
  return d;
#endif
}

// LDS arena offsets (bytes)
#define OFF_WLDS   0        // 16384  B-fragment blocks
#define OFF_AMG    16384    // 12160  95 rows x 32 words (per-wave base wv*21*32, dump row 84)
#define OFF_HLDS   28544    // 5632   fp32 master h [22][64]
#define OFF_HIBUF  34176    // 5632   hi_part f32
#define OFF_HCBUF  39808    // 5632   hc_part f32
#define OFF_AGGU   45440    // 2816   agg f16 A-tile, then u16 A-tile
#define OFF_EAS    48256    // 1848   initial sq dists f32[462]
#define OFF_EGEO   50112    // 1536   per-wave row geometry [4][24][4] f32
#define OFF_CBUF   51648    // 352    coords [22][4]
#define OFF_CUPD   52000    // 352    coord updates (vels at end)
#define OFF_VELM   52352    // 16
#define LDS_BYTES  52368

__global__ __launch_bounds__(256, 3) void egnn_kernel(
    const float* __restrict__ t,   const float* __restrict__ x,
    const float* __restrict__ embW, const float* __restrict__ embB,
    const float* __restrict__ ew1, const float* __restrict__ eb1,
    const float* __restrict__ ew2, const float* __restrict__ eb2,
    const float* __restrict__ nw1, const float* __restrict__ nb1,
    const float* __restrict__ nw2, const float* __restrict__ nb2,
    const float* __restrict__ cw1, const float* __restrict__ cb1,
    const float* __restrict__ cw2, const float* __restrict__ aw,
    const float* __restrict__ ab,  float* __restrict__ out)
{
  __shared__ __align__(16) char LDSRAW[LDS_BYTES];
  int*   wlds  = (int*)(LDSRAW + OFF_WLDS);
  int*   amg   = (int*)(LDSRAW + OFF_AMG);
  float* h_lds = (float*)(LDSRAW + OFF_HLDS);
  float* hibuf = (float*)(LDSRAW + OFF_HIBUF);
  float* hcbuf = (float*)(LDSRAW + OFF_HCBUF);
  int*   aggu  = (int*)(LDSRAW + OFF_AGGU);
  float* eas   = (float*)(LDSRAW + OFF_EAS);
  float* egeo  = (float*)(LDSRAW + OFF_EGEO);
  float* cbuf  = (float*)(LDSRAW + OFF_CBUF);
  float* cupd  = (float*)(LDSRAW + OFF_CUPD);
  float* velm  = (float*)(LDSRAW + OFF_VELM);

  const int b = blockIdx.x, tid = threadIdx.x;
  const int lane = tid & 63, wv = tid >> 6;
  const int c31 = lane & 31, hh = lane >> 5;
  const int xorv = ((lane >> 3) & 7) << 2;   // B swizzle

  auto fillblk = [&](const float* Wlo, const float* Whi, int nblocks) {
    for (int blk = wv; blk < nblocks; blk += 4) {
      const float* Ws = (blk < 8) ? Wlo : Whi;
      int kb = (blk >> 1) & 3, n = blk & 1;
      int k0 = kb * 16 + hh * 8;
      int ch = n * 32 + c31;
      int wb = blk * 256 + ((lane * 4) ^ xorv);
#pragma unroll
      for (int w = 0; w < 4; ++w) {
        h2_t p = pkf(Ws[(k0 + 2 * w) * NH + ch], Ws[(k0 + 2 * w + 1) * NH + ch]);
        wlds[wb + w] = __builtin_bit_cast(int, p);
      }
    }
  };
  auto bread = [&](int blk) -> f16x8 {
    return __builtin_bit_cast(f16x8, *(const int4*)&wlds[blk * 256 + ((lane * 4) ^ xorv)]);
  };
  auto aread = [&](const int* tile, int ks) -> f16x8 {
    int off = (ks * 8 + hh * 4) ^ ((c31 & 7) << 2);
    return __builtin_bit_cast(f16x8, *(const int4*)&tile[c31 * 32 + off]);
  };
  auto packh = [&]() {
    for (int idx = tid; idx < NP * 32; idx += 256) {
      int atom = idx >> 5, w = idx & 31;
      h2_t p = pkf(h_lds[atom * 64 + 2 * w], h_lds[atom * 64 + 2 * w + 1]);
      amg[atom * 32 + (w ^ ((atom & 7) << 2))] = __builtin_bit_cast(int, p);
    }
  };

  // ---- init
  if (tid < NP * 3) {
    int p = tid / 3, c = tid - p * 3;
    cbuf[p * 4 + c] = x[b * (NP * 3) + tid];
  }
  float tb = t[b];
  for (int p = wv; p < NP; p += 4)
    h_lds[p * 64 + lane] = embW[p * NH + lane] + tb * embW[22 * NH + lane]
                         + LOG2Mc * embW[23 * NH + lane] + embB[lane];
  __syncthreads();
  for (int idx = tid; idx < NP * NE; idx += 256) {
    int r = idx / NE, e = idx - r * NE, col = e + (e >= r);
    float dx = cbuf[r * 4 + 0] - cbuf[col * 4 + 0];
    float dy = cbuf[r * 4 + 1] - cbuf[col * 4 + 1];
    float dz = cbuf[r * 4 + 2] - cbuf[col * 4 + 2];
    eas[idx] = dx * dx + dy * dy + dz * dz;
  }
  __syncthreads();

  for (int l = 0; l < NL; ++l) {
    const float* W1 = ew1 + l * 130 * NH;
    const float* W2 = ew2 + l * NH * NH;
    const float* C1 = cw1 + l * NH * NH;
    const float* N1 = nw1 + l * 128 * NH;
    const float* N2 = nw2 + l * NH * NH;

    // ---- step1: wlds <- W1 rows 0..127; pack h A-tile into amg
    fillblk(W1, W1 + 64 * NH, 16);
    packh();
    __syncthreads();

    // ---- step2: phase0 — hi (waves 0,1) / hc (waves 2,3)
    {
      int s = wv >> 1, n = wv & 1;
      f32x16 acc;
#pragma unroll
      for (int i = 0; i < 16; ++i) acc[i] = 0.f;
#pragma unroll
      for (int ks = 0; ks < 4; ++ks)
        acc = __builtin_amdgcn_mfma_f32_32x32x16_f16(aread(amg, ks),
                bread((s * 4 + ks) * 2 + n), acc, 0, 0, 0);
      int ch = n * 32 + c31;
      float bias = (s == 0) ? eb1[l * NH + ch] : 0.0f;
      float* dst = (s == 0) ? hibuf : hcbuf;
#pragma unroll
      for (int q = 0; q < 16; ++q) {
        int atom = (q & 3) + 8 * (q >> 2) + 4 * hh;
        if (atom < NP) dst[atom * 64 + ch] = acc[q] + bias;
      }
    }
    __syncthreads();

    // ---- step3: wlds <- W2 (blocks 0-7), C1 (blocks 8-15)
    fillblk(W2, C1, 16);
    __syncthreads();

    // ---- step4: edge phase
    float w128r = W1[128 * NH + lane], w129r = W1[129 * NH + lane];
    float b2r0 = eb2[l * NH + c31],  b2r1 = eb2[l * NH + 32 + c31];
    float abl  = ab[l];
    float cb1r0 = cb1[l * NH + c31], cb1r1 = cb1[l * NH + 32 + c31];
    float c2r0 = cw2[l * NH + c31],  c2r1 = cw2[l * NH + 32 + c31];
    h2_t  awT  = pkf(aw[l * NH + 2 * c31], aw[l * NH + 2 * c31 + 1]);

    const int abase = wv * (NE * 32);
    for (int r = wv; r < NP; r += 4) {
      // per-lane edge geometry (lane = edge index)
      int eL = (lane < NE) ? lane : NE - 1;
      int colL = eL + (eL >= r);
      float4 ccL = *(const float4*)&cbuf[colL * 4];
      float4 crL = *(const float4*)&cbuf[r * 4];
      float gdx = crL.x - ccL.x, gdy = crL.y - ccL.y, gdz = crL.z - ccL.z;
      float radialT = gdx * gdx + gdy * gdy + gdz * gdz;
      float ndT = rcp_(sqrt_(radialT) + 1.0f);
      if (lane < NE) {
        float4 gw = {gdx, gdy, gdz, ndT};
        *(float4*)&egeo[(wv * 24 + lane) * 4] = gw;
      }
      float eaT = eas[r * NE + eL];
      float hii = hibuf[r * 64 + lane];

      // phase1: m1 for 21 edges, staged full-rate in pairs
#pragma unroll
      for (int e2 = 0; e2 < 20; e2 += 2) {
        int ea_ = e2, eb_ = e2 + 1;
        int cola = ea_ + (ea_ >= r), colb = eb_ + (eb_ >= r);
        float ra = rl_f(radialT, ea_), rb = rl_f(radialT, eb_);
        float qa = rl_f(eaT, ea_),     qb = rl_f(eaT, eb_);
        float s1a = hii + hcbuf[cola * 64 + lane];
        s1a = fmaf(ra, w128r, s1a); s1a = fmaf(qa, w129r, s1a);
        float s1b = hii + hcbuf[colb * 64 + lane];
        s1b = fmaf(rb, w128r, s1b); s1b = fmaf(qb, w129r, s1b);
        float m1a = siluf(s1a), m1b = siluf(s1b);
        h2_t wa = pkf(m1a, dppmov<0xB1>(m1a));   // valid even lanes
        h2_t wb = pkf(dppmov<0xB1>(m1b), m1b);   // valid odd lanes
        int row = (lane & 1) ? eb_ : ea_;
        int w = lane >> 1;
        amg[abase + row * 32 + (w ^ ((row & 7) << 2))] =
            (lane & 1) ? __builtin_bit_cast(int, wb) : __builtin_bit_cast(int, wa);
      }
      { // tail edge 20
        int col20 = 20 + (20 >= r);
        col20 = (col20 < NP) ? col20 : 20;
        float ra = rl_f(radialT, 20), qa = rl_f(eaT, 20);
        float s1 = hii + hcbuf[col20 * 64 + lane];
        s1 = fmaf(ra, w128r, s1); s1 = fmaf(qa, w129r, s1);
        float m1 = siluf(s1);
        h2_t wa = pkf(m1, dppmov<0xB1>(m1));
        if (!(lane & 1))
          amg[abase + 20 * 32 + ((lane >> 1) ^ ((20 & 7) << 2))] = __builtin_bit_cast(int, wa);
      }

      // pass1: m1 @ W2
      f32x16 acc0, acc1;
#pragma unroll
      for (int i = 0; i < 16; ++i) { acc0[i] = 0.f; acc1[i] = 0.f; }
#pragma unroll
      for (int ks = 0; ks < 4; ++ks) {
        f16x8 af = aread(&amg[abase], ks);
        acc0 = __builtin_amdgcn_mfma_f32_32x32x16_f16(af, bread(ks * 2 + 0), acc0, 0, 0, 0);
        acc1 = __builtin_amdgcn_mfma_f32_32x32x16_f16(af, bread(ks * 2 + 1), acc1, 0, 0, 0);
      }

      // post1: m2 = silu(s2 + b2); restage m2; invalid rows (rowq>=NE) -> dump row 84
#pragma unroll
      for (int q = 0; q < 16; ++q) {
        int e0 = (q & 3) + 8 * (q >> 2);     // e0 in {0..3,8..11,16..19,24..27}
        int rowq = e0 + 4 * hh;
        float m20 = siluf(acc0[q] + b2r0);
        float m21 = siluf(acc1[q] + b2r1);
        acc0[q] = m20; acc1[q] = m21;
        h2_t w0 = pkf(m20, dppmov<0xB1>(m20));   // even lanes
        h2_t w1 = pkf(dppmov<0xB1>(m21), m21);   // odd lanes
        int wq = (lane & 1) ? 16 + (c31 >> 1) : (c31 >> 1);
        int adr = (rowq < NE) ? (abase + rowq * 32 + (wq ^ ((rowq & 7) << 2)))
                              : (84 * 32 + wq);
        amg[adr] = (lane & 1) ? __builtin_bit_cast(int, w1) : __builtin_bit_cast(int, w0);
      }

      // gate: lane = edge, 64-ch dot over staged m2 tile
      float gg = 0.f;
      {
        int xr = (c31 & 7) << 2;
#pragma unroll
        for (int tt = 0; tt < 8; ++tt) {
          int4 v4 = *(const int4*)&amg[abase + c31 * 32 + ((4 * tt) ^ xr)];
          gg = fdot2(__builtin_bit_cast(h2_t, v4.x), rl_h2(awT, 4 * tt + 0), gg);
          gg = fdot2(__builtin_bit_cast(h2_t, v4.y), rl_h2(awT, 4 * tt + 1), gg);
          gg = fdot2(__builtin_bit_cast(h2_t, v4.z), rl_h2(awT, 4 * tt + 2), gg);
          gg = fdot2(__builtin_bit_cast(h2_t, v4.w), rl_h2(awT, 4 * tt + 3), gg);
        }
      }
      float sgT = sigf(gg + abl);                // valid in lanes 0..20

      // pass2: m2 @ C1
      f32x16 acc2, acc3;
#pragma unroll
      for (int i = 0; i < 16; ++i) { acc2[i] = 0.f; acc3[i] = 0.f; }
#pragma unroll
      for (int ks = 0; ks < 4; ++ks) {
        f16x8 af = aread(&amg[abase], ks);
        acc2 = __builtin_amdgcn_mfma_f32_32x32x16_f16(af, bread(8 + ks * 2 + 0), acc2, 0, 0, 0);
        acc3 = __builtin_amdgcn_mfma_f32_32x32x16_f16(af, bread(8 + ks * 2 + 1), acc3, 0, 0, 0);
      }

      // post2: sg scaling, agg, coord MLP epilogue — NaN-safe selects on rowq<NE
      float aggn0 = 0.f, aggn1 = 0.f, cax = 0.f, cay = 0.f, caz = 0.f;
#pragma unroll
      for (int q = 0; q < 16; ++q) {
        int e0 = (q & 3) + 8 * (q >> 2);
        int rowq = e0 + 4 * hh;
        bool valid = (rowq < NE);
        float sg = hh ? rl_f(sgT, e0 + 4) : rl_f(sgT, e0);
        float ca0 = acc0[q] * sg, ca1 = acc1[q] * sg;
        aggn0 += valid ? ca0 : 0.f;              // select, not multiply-by-0
        aggn1 += valid ? ca1 : 0.f;
        float c10 = siluf(fmaf(sg, acc2[q], cb1r0));
        float c11 = siluf(fmaf(sg, acc3[q], cb1r1));
        float d = red32(c10 * c2r0 + c11 * c2r1);
        float th = 1.0f - 2.0f * rcp_(1.0f + exp2_(2.0f * L2E * d));
        int eg = valid ? rowq : 0;               // clamped in-bounds read
        float4 ge = *(const float4*)&egeo[(wv * 24 + eg) * 4];
        float f = valid ? (th * CRc * ge.w) : 0.f;
        cax = fmaf(ge.x, f, cax);
        cay = fmaf(ge.y, f, cay);
        caz = fmaf(ge.z, f, caz);
      }
      aggn0 += __shfl_xor(aggn0, 32, 64);
      aggn1 += __shfl_xor(aggn1, 32, 64);
      { // write agg directly as f16 A-tile row r
        h2_t a0p = pkf(aggn0, dppmov<0xB1>(aggn0));   // even lanes
        h2_t a1p = pkf(dppmov<0xB1>(aggn1), aggn1);   // odd lanes
        if (lane < 32) {
          int wq = (lane & 1) ? 16 + (c31 >> 1) : (c31 >> 1);
          aggu[r * 32 + (wq ^ ((r & 7) << 2))] =
              (lane & 1) ? __builtin_bit_cast(int, a1p) : __builtin_bit_cast(int, a0p);
        }
      }
      cax += __shfl_xor(cax, 32, 64);
      cay += __shfl_xor(cay, 32, 64);
      caz += __shfl_xor(caz, 32, 64);
      if (lane < 3) {
        float cv = (lane == 0) ? cax : (lane == 1) ? cay : caz;
        cupd[r * 4 + lane] = cv;
      }
    }
    __syncthreads();

    // ---- step5: wlds <- N1; repack h A-tile
    fillblk(N1, N1 + 64 * NH, 16);
    packh();
    __syncthreads();

    // ---- step6: u = silu(h@N1lo + agg@N1hi + nb1) -> f16 pairs in regs
    int uw[16];
    if (wv < 2) {
      int n = wv;
      f32x16 acc;
#pragma unroll
      for (int i = 0; i < 16; ++i) acc[i] = 0.f;
#pragma unroll
      for (int ks = 0; ks < 4; ++ks)
        acc = __builtin_amdgcn_mfma_f32_32x32x16_f16(aread(amg, ks),
                bread(ks * 2 + n), acc, 0, 0, 0);
#pragma unroll
      for (int ks = 0; ks < 4; ++ks)
        acc = __builtin_amdgcn_mfma_f32_32x32x16_f16(aread(aggu, ks),
                bread((4 + ks) * 2 + n), acc, 0, 0, 0);
      float bias = nb1[l * NH + n * 32 + c31];
#pragma unroll
      for (int q = 0; q < 16; ++q) {
        float v = siluf(acc[q] + bias);
        h2_t p = pkf(v, dppmov<0xB1>(v));        // even lanes
        uw[q] = __builtin_bit_cast(int, p);
      }
    }
    __syncthreads();

    // ---- step7: wlds <- N2; write u16 tile over aggu
    fillblk(N2, N2, 8);
    if (wv < 2 && !(lane & 1)) {
      int n = wv;
#pragma unroll
      for (int q = 0; q < 16; ++q) {
        int atom = (q & 3) + 8 * (q >> 2) + 4 * hh;
        if (atom < NP)
          aggu[atom * 32 + ((16 * n + (c31 >> 1)) ^ ((atom & 7) << 2))] = uw[q];
      }
    }
    __syncthreads();

    // ---- step8: h += u16@N2 + nb2 (waves 0,1); coords += cupd (waves 2,3)
    if (wv < 2) {
      int n = wv;
      f32x16 acc;
#pragma unroll
      for (int i = 0; i < 16; ++i) acc[i] = 0.f;
#pragma unroll
      for (int ks = 0; ks < 4; ++ks)
        acc = __builtin_amdgcn_mfma_f32_32x32x16_f16(aread(aggu, ks),
                bread(ks * 2 + n), acc, 0, 0, 0);
      int ch = n * 32 + c31;
      float bias = nb2[l * NH + ch];
#pragma unroll
      for (int q = 0; q < 16; ++q) {
        int atom = (q & 3) + 8 * (q >> 2) + 4 * hh;
        if (atom < NP) h_lds[atom * 64 + ch] += acc[q] + bias;
      }
    } else {
      int ci = tid - 128;
      if (ci < NP * 3) {
        int p = ci / 3, c = ci - 3 * p;
        cbuf[p * 4 + c] += cupd[p * 4 + c];
      }
    }
    __syncthreads();
  }

  // ---- output: vel = coord - coord0 (re-read x), mean-removed
  if (tid < NP * 3) {
    int p = tid / 3, c = tid - p * 3;
    cupd[p * 4 + c] = cbuf[p * 4 + c] - x[b * (NP * 3) + tid];
  }
  __syncthreads();
  if (tid < 3) {
    float s = 0.f;
    for (int p = 0; p < NP; ++p) s += cupd[p * 4 + tid];
    velm[tid] = s * (1.0f / 22.0f);
  }
  __syncthreads();
  if (tid < NP * 3) {
    int p = tid / 3, c = tid - p * 3;
    out[b * (NP * 3) + tid] = cupd[p * 4 + c] - velm[c];
  }
}

extern "C" void kernel_launch(void* const* d_in, const int* in_sizes, int n_in,
                              void* d_out, int out_size, void* d_ws, size_t ws_size,
                              hipStream_t stream) {
  const float* t    = (const float*)d_in[0];
  const float* x    = (const float*)d_in[1];
  const float* embW = (const float*)d_in[2];
  const float* embB = (const float*)d_in[3];
  // d_in[4] out_W, d_in[5] out_b: do not affect the returned velocities
  const float* ew1  = (const float*)d_in[6];
  const float* eb1  = (const float*)d_in[7];
  const float* ew2  = (const float*)d_in[8];
  const float* eb2  = (const float*)d_in[9];
  const float* nw1  = (const float*)d_in[10];
  const float* nb1  = (const float*)d_in[11];
  const float* nw2  = (const float*)d_in[12];
  const float* nb2  = (const float*)d_in[13];
  const float* cw1  = (const float*)d_in[14];
  const float* cb1  = (const float*)d_in[15];
  const float* cw2  = (const float*)d_in[16];
  const float* aw   = (const float*)d_in[17];
  const float* ab   = (const float*)d_in[18];
  // d_in[19] rows, d_in[20] cols: edge list regenerated analytically in-kernel

  egnn_kernel<<<1024, 256, 0, stream>>>(t, x, embW, embB, ew1, eb1, ew2, eb2,
                                        nw1, nb1, nw2, nb2, cw1, cb1, cw2,
                                        aw, ab, (float*)d_out);
}

// Round 8
// 472.518 us; speedup vs baseline: 1.8686x; 1.8686x over previous
//
#include <hip/hip_runtime.h>

#define NP 22
#define NH 64
#define NL 5
#define NE 21

constexpr float CRc    = 3.0f;   // 15/L
constexpr float LOG2Mc = 7.0f;
constexpr float L2E    = 1.442695041f;

typedef __fp16 h2_t  __attribute__((ext_vector_type(2)));
typedef __fp16 f16x8 __attribute__((ext_vector_type(8)));
typedef float  f32x16 __attribute__((ext_vector_type(16)));

// ---- native single-instruction transcendentals
__device__ __forceinline__ float rcp_(float x) {
#if __has_builtin(__builtin_amdgcn_rcpf)
  return __builtin_amdgcn_rcpf(x);
#else
  float r; asm("v_rcp_f32 %0, %1" : "=v"(r) : "v"(x)); return r;
#endif
}
__device__ __forceinline__ float exp2_(float x) {
#if __has_builtin(__builtin_amdgcn_exp2f)
  return __builtin_amdgcn_exp2f(x);
#else
  float r; asm("v_exp_f32 %0, %1" : "=v"(r) : "v"(x)); return r;
#endif
}
__device__ __forceinline__ float sqrt_(float x) {
#if __has_builtin(__builtin_amdgcn_sqrtf)
  return __builtin_amdgcn_sqrtf(x);
#else
  float r; asm("v_sqrt_f32 %0, %1" : "=v"(r) : "v"(x)); return r;
#endif
}
__device__ __forceinline__ float sigf(float s)  { return rcp_(1.0f + exp2_(-L2E * s)); }
__device__ __forceinline__ float siluf(float s) { return s * sigf(s); }

__device__ __forceinline__ float rl_f(float v, int lane) {
  return __builtin_bit_cast(float, __builtin_amdgcn_readlane(__builtin_bit_cast(int, v), lane));
}
__device__ __forceinline__ h2_t rl_h2(h2_t v, int lane) {
  return __builtin_bit_cast(h2_t, __builtin_amdgcn_readlane(__builtin_bit_cast(int, v), lane));
}
__device__ __forceinline__ h2_t pkf(float a, float b) {
  return __builtin_amdgcn_cvt_pkrtz(a, b);
}
template <int CTRL>
__device__ __forceinline__ float dppmov(float v) {
  return __builtin_bit_cast(float,
      __builtin_amdgcn_update_dpp(0, __builtin_bit_cast(int, v), CTRL, 0xF, 0xF, true));
}
// sum over each 32-lane group
__device__ __forceinline__ float red32(float v) {
  v += dppmov<0xB1>(v);
  v += dppmov<0x4E>(v);
  v += dppmov<0x124>(v);
  v += dppmov<0x128>(v);
  v += __builtin_bit_cast(float, __builtin_amdgcn_ds_swizzle(
         __builtin_bit_cast(int, v), 0x401F));
  return v;
}
__device__ __forceinline__ float fdot2(h2_t a, h2_t b, float c) {
#if __has_builtin(__builtin_amdgcn_fdot2)
  return __builtin_amdgcn_fdot2(a, b, c, false);
#else
  float d;
  asm("v_dot2_f32_f16 %0, %1, %2, %3"
      : "=v"(d)
      : "v"(__builtin_bit_cast(int, a)), "v"(__builtin_bit_cast(int, b)), "v"(c));
  return d;
#endif
}

// LDS arena offsets (bytes)
#define OFF_WLDS   0        // 16384  B-fragment blocks
#define OFF_AMG    16384    // 12160  95 rows x 32 words (per-wave base wv*21*32, dump row 84)
#define OFF_HLDS   28544    // 5632   fp32 master h [22][64]
#define OFF_HIBUF  34176    // 5632   hi_part f32
#define OFF_HCBUF  39808    // 5632   hc_part f32
#define OFF_AGGU   45440    // 2816   agg f16 A-tile, then u16 A-tile
#define OFF_EAS    48256    // 1848   initial sq dists f32[462]
#define OFF_EGEO   50112    // 1536   per-wave row geometry [4][24][4] f32
#define OFF_CBUF   51648    // 352    coords [22][4]
#define OFF_CUPD   52000    // 352    coord updates (vels at end)
#define OFF_VELM   52352    // 16
#define LDS_BYTES  52368

__global__ __launch_bounds__(256, 2) void egnn_kernel(
    const float* __restrict__ t,   const float* __restrict__ x,
    const float* __restrict__ embW, const float* __restrict__ embB,
    const float* __restrict__ ew1, const float* __restrict__ eb1,
    const float* __restrict__ ew2, const float* __restrict__ eb2,
    const float* __restrict__ nw1, const float* __restrict__ nb1,
    const float* __restrict__ nw2, const float* __restrict__ nb2,
    const float* __restrict__ cw1, const float* __restrict__ cb1,
    const float* __restrict__ cw2, const float* __restrict__ aw,
    const float* __restrict__ ab,  float* __restrict__ out)
{
  __shared__ __align__(16) char LDSRAW[LDS_BYTES];
  int*   wlds  = (int*)(LDSRAW + OFF_WLDS);
  int*   amg   = (int*)(LDSRAW + OFF_AMG);
  float* h_lds = (float*)(LDSRAW + OFF_HLDS);
  float* hibuf = (float*)(LDSRAW + OFF_HIBUF);
  float* hcbuf = (float*)(LDSRAW + OFF_HCBUF);
  int*   aggu  = (int*)(LDSRAW + OFF_AGGU);
  float* eas   = (float*)(LDSRAW + OFF_EAS);
  float* egeo  = (float*)(LDSRAW + OFF_EGEO);
  float* cbuf  = (float*)(LDSRAW + OFF_CBUF);
  float* cupd  = (float*)(LDSRAW + OFF_CUPD);
  float* velm  = (float*)(LDSRAW + OFF_VELM);

  const int b = blockIdx.x, tid = threadIdx.x;
  const int lane = tid & 63, wv = tid >> 6;
  const int c31 = lane & 31, hh = lane >> 5;
  const int xorv = ((lane >> 3) & 7) << 2;   // B swizzle

  auto fillblk = [&](const float* Wlo, const float* Whi, int nblocks) {
    for (int blk = wv; blk < nblocks; blk += 4) {
      const float* Ws = (blk < 8) ? Wlo : Whi;
      int kb = (blk >> 1) & 3, n = blk & 1;
      int k0 = kb * 16 + hh * 8;
      int ch = n * 32 + c31;
      int wb = blk * 256 + ((lane * 4) ^ xorv);
#pragma unroll
      for (int w = 0; w < 4; ++w) {
        h2_t p = pkf(Ws[(k0 + 2 * w) * NH + ch], Ws[(k0 + 2 * w + 1) * NH + ch]);
        wlds[wb + w] = __builtin_bit_cast(int, p);
      }
    }
  };
  auto bread = [&](int blk) -> f16x8 {
    return __builtin_bit_cast(f16x8, *(const int4*)&wlds[blk * 256 + ((lane * 4) ^ xorv)]);
  };
  auto aread = [&](const int* tile, int ks) -> f16x8 {
    int off = (ks * 8 + hh * 4) ^ ((c31 & 7) << 2);
    return __builtin_bit_cast(f16x8, *(const int4*)&tile[c31 * 32 + off]);
  };
  auto packh = [&]() {
    for (int idx = tid; idx < NP * 32; idx += 256) {
      int atom = idx >> 5, w = idx & 31;
      h2_t p = pkf(h_lds[atom * 64 + 2 * w], h_lds[atom * 64 + 2 * w + 1]);
      amg[atom * 32 + (w ^ ((atom & 7) << 2))] = __builtin_bit_cast(int, p);
    }
  };

  // ---- init
  if (tid < NP * 3) {
    int p = tid / 3, c = tid - p * 3;
    cbuf[p * 4 + c] = x[b * (NP * 3) + tid];
  }
  float tb = t[b];
  for (int p = wv; p < NP; p += 4)
    h_lds[p * 64 + lane] = embW[p * NH + lane] + tb * embW[22 * NH + lane]
                         + LOG2Mc * embW[23 * NH + lane] + embB[lane];
  __syncthreads();
  for (int idx = tid; idx < NP * NE; idx += 256) {
    int r = idx / NE, e = idx - r * NE, col = e + (e >= r);
    float dx = cbuf[r * 4 + 0] - cbuf[col * 4 + 0];
    float dy = cbuf[r * 4 + 1] - cbuf[col * 4 + 1];
    float dz = cbuf[r * 4 + 2] - cbuf[col * 4 + 2];
    eas[idx] = dx * dx + dy * dy + dz * dz;
  }
  __syncthreads();

  for (int l = 0; l < NL; ++l) {
    const float* W1 = ew1 + l * 130 * NH;
    const float* W2 = ew2 + l * NH * NH;
    const float* C1 = cw1 + l * NH * NH;
    const float* N1 = nw1 + l * 128 * NH;
    const float* N2 = nw2 + l * NH * NH;

    // ---- step1: wlds <- W1 rows 0..127; pack h A-tile into amg
    fillblk(W1, W1 + 64 * NH, 16);
    packh();
    __syncthreads();

    // ---- step2: phase0 — hi (waves 0,1) / hc (waves 2,3)
    {
      int s = wv >> 1, n = wv & 1;
      f32x16 acc;
#pragma unroll
      for (int i = 0; i < 16; ++i) acc[i] = 0.f;
#pragma unroll
      for (int ks = 0; ks < 4; ++ks)
        acc = __builtin_amdgcn_mfma_f32_32x32x16_f16(aread(amg, ks),
                bread((s * 4 + ks) * 2 + n), acc, 0, 0, 0);
      int ch = n * 32 + c31;
      float bias = (s == 0) ? eb1[l * NH + ch] : 0.0f;
      float* dst = (s == 0) ? hibuf : hcbuf;
#pragma unroll
      for (int q = 0; q < 16; ++q) {
        int atom = (q & 3) + 8 * (q >> 2) + 4 * hh;
        if (atom < NP) dst[atom * 64 + ch] = acc[q] + bias;
      }
    }
    __syncthreads();

    // ---- step3: wlds <- W2 (blocks 0-7), C1 (blocks 8-15)
    fillblk(W2, C1, 16);
    __syncthreads();

    // ---- step4: edge phase
    float w128r = W1[128 * NH + lane], w129r = W1[129 * NH + lane];
    float b2r0 = eb2[l * NH + c31],  b2r1 = eb2[l * NH + 32 + c31];
    float abl  = ab[l];
    float cb1r0 = cb1[l * NH + c31], cb1r1 = cb1[l * NH + 32 + c31];
    float c2r0 = cw2[l * NH + c31],  c2r1 = cw2[l * NH + 32 + c31];
    h2_t  awT  = pkf(aw[l * NH + 2 * c31], aw[l * NH + 2 * c31 + 1]);

    const int abase = wv * (NE * 32);
    for (int r = wv; r < NP; r += 4) {
      // per-lane edge geometry (lane = edge index)
      int eL = (lane < NE) ? lane : NE - 1;
      int colL = eL + (eL >= r);
      float4 ccL = *(const float4*)&cbuf[colL * 4];
      float4 crL = *(const float4*)&cbuf[r * 4];
      float gdx = crL.x - ccL.x, gdy = crL.y - ccL.y, gdz = crL.z - ccL.z;
      float radialT = gdx * gdx + gdy * gdy + gdz * gdz;
      float ndT = rcp_(sqrt_(radialT) + 1.0f);
      if (lane < NE) {
        float4 gw = {gdx, gdy, gdz, ndT};
        *(float4*)&egeo[(wv * 24 + lane) * 4] = gw;
      }
      float eaT = eas[r * NE + eL];
      float hii = hibuf[r * 64 + lane];

      // phase1: m1 for 21 edges, staged full-rate in pairs
#pragma unroll
      for (int e2 = 0; e2 < 20; e2 += 2) {
        int ea_ = e2, eb_ = e2 + 1;
        int cola = ea_ + (ea_ >= r), colb = eb_ + (eb_ >= r);
        float ra = rl_f(radialT, ea_), rb = rl_f(radialT, eb_);
        float qa = rl_f(eaT, ea_),     qb = rl_f(eaT, eb_);
        float s1a = hii + hcbuf[cola * 64 + lane];
        s1a = fmaf(ra, w128r, s1a); s1a = fmaf(qa, w129r, s1a);
        float s1b = hii + hcbuf[colb * 64 + lane];
        s1b = fmaf(rb, w128r, s1b); s1b = fmaf(qb, w129r, s1b);
        float m1a = siluf(s1a), m1b = siluf(s1b);
        h2_t wa = pkf(m1a, dppmov<0xB1>(m1a));   // valid even lanes
        h2_t wb = pkf(dppmov<0xB1>(m1b), m1b);   // valid odd lanes
        int row = (lane & 1) ? eb_ : ea_;
        int w = lane >> 1;
        amg[abase + row * 32 + (w ^ ((row & 7) << 2))] =
            (lane & 1) ? __builtin_bit_cast(int, wb) : __builtin_bit_cast(int, wa);
      }
      { // tail edge 20
        int col20 = 20 + (20 >= r);
        col20 = (col20 < NP) ? col20 : 20;
        float ra = rl_f(radialT, 20), qa = rl_f(eaT, 20);
        float s1 = hii + hcbuf[col20 * 64 + lane];
        s1 = fmaf(ra, w128r, s1); s1 = fmaf(qa, w129r, s1);
        float m1 = siluf(s1);
        h2_t wa = pkf(m1, dppmov<0xB1>(m1));
        if (!(lane & 1))
          amg[abase + 20 * 32 + ((lane >> 1) ^ ((20 & 7) << 2))] = __builtin_bit_cast(int, wa);
      }

      // pass1: m1 @ W2
      f32x16 acc0, acc1;
#pragma unroll
      for (int i = 0; i < 16; ++i) { acc0[i] = 0.f; acc1[i] = 0.f; }
#pragma unroll
      for (int ks = 0; ks < 4; ++ks) {
        f16x8 af = aread(&amg[abase], ks);
        acc0 = __builtin_amdgcn_mfma_f32_32x32x16_f16(af, bread(ks * 2 + 0), acc0, 0, 0, 0);
        acc1 = __builtin_amdgcn_mfma_f32_32x32x16_f16(af, bread(ks * 2 + 1), acc1, 0, 0, 0);
      }

      // post1: m2 = silu(s2 + b2); restage m2; invalid rows (rowq>=NE) -> dump row 84
#pragma unroll
      for (int q = 0; q < 16; ++q) {
        int e0 = (q & 3) + 8 * (q >> 2);     // e0 in {0..3,8..11,16..19,24..27}
        int rowq = e0 + 4 * hh;
        float m20 = siluf(acc0[q] + b2r0);
        float m21 = siluf(acc1[q] + b2r1);
        acc0[q] = m20; acc1[q] = m21;
        h2_t w0 = pkf(m20, dppmov<0xB1>(m20));   // even lanes
        h2_t w1 = pkf(dppmov<0xB1>(m21), m21);   // odd lanes
        int wq = (lane & 1) ? 16 + (c31 >> 1) : (c31 >> 1);
        int adr = (rowq < NE) ? (abase + rowq * 32 + (wq ^ ((rowq & 7) << 2)))
                              : (84 * 32 + wq);
        amg[adr] = (lane & 1) ? __builtin_bit_cast(int, w1) : __builtin_bit_cast(int, w0);
      }

      // gate: lane = edge, 64-ch dot over staged m2 tile
      float gg = 0.f;
      {
        int xr = (c31 & 7) << 2;
#pragma unroll
        for (int tt = 0; tt < 8; ++tt) {
          int4 v4 = *(const int4*)&amg[abase + c31 * 32 + ((4 * tt) ^ xr)];
          gg = fdot2(__builtin_bit_cast(h2_t, v4.x), rl_h2(awT, 4 * tt + 0), gg);
          gg = fdot2(__builtin_bit_cast(h2_t, v4.y), rl_h2(awT, 4 * tt + 1), gg);
          gg = fdot2(__builtin_bit_cast(h2_t, v4.z), rl_h2(awT, 4 * tt + 2), gg);
          gg = fdot2(__builtin_bit_cast(h2_t, v4.w), rl_h2(awT, 4 * tt + 3), gg);
        }
      }
      float sgT = sigf(gg + abl);                // valid in lanes 0..20

      // pass2: m2 @ C1
      f32x16 acc2, acc3;
#pragma unroll
      for (int i = 0; i < 16; ++i) { acc2[i] = 0.f; acc3[i] = 0.f; }
#pragma unroll
      for (int ks = 0; ks < 4; ++ks) {
        f16x8 af = aread(&amg[abase], ks);
        acc2 = __builtin_amdgcn_mfma_f32_32x32x16_f16(af, bread(8 + ks * 2 + 0), acc2, 0, 0, 0);
        acc3 = __builtin_amdgcn_mfma_f32_32x32x16_f16(af, bread(8 + ks * 2 + 1), acc3, 0, 0, 0);
      }

      // post2: sg scaling, agg, coord MLP epilogue — NaN-safe selects on rowq<NE
      float aggn0 = 0.f, aggn1 = 0.f, cax = 0.f, cay = 0.f, caz = 0.f;
#pragma unroll
      for (int q = 0; q < 16; ++q) {
        int e0 = (q & 3) + 8 * (q >> 2);
        int rowq = e0 + 4 * hh;
        bool valid = (rowq < NE);
        float sg = hh ? rl_f(sgT, e0 + 4) : rl_f(sgT, e0);
        float ca0 = acc0[q] * sg, ca1 = acc1[q] * sg;
        aggn0 += valid ? ca0 : 0.f;              // select, not multiply-by-0
        aggn1 += valid ? ca1 : 0.f;
        float c10 = siluf(fmaf(sg, acc2[q], cb1r0));
        float c11 = siluf(fmaf(sg, acc3[q], cb1r1));
        float d = red32(c10 * c2r0 + c11 * c2r1);
        float th = 1.0f - 2.0f * rcp_(1.0f + exp2_(2.0f * L2E * d));
        int eg = valid ? rowq : 0;               // clamped in-bounds read
        float4 ge = *(const float4*)&egeo[(wv * 24 + eg) * 4];
        float f = valid ? (th * CRc * ge.w) : 0.f;
        cax = fmaf(ge.x, f, cax);
        cay = fmaf(ge.y, f, cay);
        caz = fmaf(ge.z, f, caz);
      }
      aggn0 += __shfl_xor(aggn0, 32, 64);
      aggn1 += __shfl_xor(aggn1, 32, 64);
      { // write agg directly as f16 A-tile row r
        h2_t a0p = pkf(aggn0, dppmov<0xB1>(aggn0));   // even lanes
        h2_t a1p = pkf(dppmov<0xB1>(aggn1), aggn1);   // odd lanes
        if (lane < 32) {
          int wq = (lane & 1) ? 16 + (c31 >> 1) : (c31 >> 1);
          aggu[r * 32 + (wq ^ ((r & 7) << 2))] =
              (lane & 1) ? __builtin_bit_cast(int, a1p) : __builtin_bit_cast(int, a0p);
        }
      }
      cax += __shfl_xor(cax, 32, 64);
      cay += __shfl_xor(cay, 32, 64);
      caz += __shfl_xor(caz, 32, 64);
      if (lane < 3) {
        float cv = (lane == 0) ? cax : (lane == 1) ? cay : caz;
        cupd[r * 4 + lane] = cv;
      }
    }
    __syncthreads();

    // ---- step5: wlds <- N1; repack h A-tile
    fillblk(N1, N1 + 64 * NH, 16);
    packh();
    __syncthreads();

    // ---- step6: u = silu(h@N1lo + agg@N1hi + nb1), written to hibuf (ubuf)
    if (wv < 2) {
      int n = wv;
      f32x16 acc;
#pragma unroll
      for (int i = 0; i < 16; ++i) acc[i] = 0.f;
#pragma unroll
      for (int ks = 0; ks < 4; ++ks)
        acc = __builtin_amdgcn_mfma_f32_32x32x16_f16(aread(amg, ks),
                bread(ks * 2 + n), acc, 0, 0, 0);
#pragma unroll
      for (int ks = 0; ks < 4; ++ks)
        acc = __builtin_amdgcn_mfma_f32_32x32x16_f16(aread(aggu, ks),
                bread((4 + ks) * 2 + n), acc, 0, 0, 0);
      float bias = nb1[l * NH + n * 32 + c31];
#pragma unroll
      for (int q = 0; q < 16; ++q) {
        int atom = (q & 3) + 8 * (q >> 2) + 4 * hh;
        if (atom < NP) hibuf[atom * 64 + n * 32 + c31] = acc[q] + bias;
      }
    }
    __syncthreads();

    // ---- step7: wlds <- N2; u16 tile over aggu from silu(ubuf)
    fillblk(N2, N2, 8);
    for (int idx = tid; idx < NP * 32; idx += 256) {
      int atom = idx >> 5, w = idx & 31;
      h2_t p = pkf(siluf(hibuf[atom * 64 + 2 * w]), siluf(hibuf[atom * 64 + 2 * w + 1]));
      aggu[atom * 32 + (w ^ ((atom & 7) << 2))] = __builtin_bit_cast(int, p);
    }
    __syncthreads();

    // ---- step8: h += u16@N2 + nb2 (waves 0,1); coords += cupd (waves 2,3)
    if (wv < 2) {
      int n = wv;
      f32x16 acc;
#pragma unroll
      for (int i = 0; i < 16; ++i) acc[i] = 0.f;
#pragma unroll
      for (int ks = 0; ks < 4; ++ks)
        acc = __builtin_amdgcn_mfma_f32_32x32x16_f16(aread(aggu, ks),
                bread(ks * 2 + n), acc, 0, 0, 0);
      int ch = n * 32 + c31;
      float bias = nb2[l * NH + ch];
#pragma unroll
      for (int q = 0; q < 16; ++q) {
        int atom = (q & 3) + 8 * (q >> 2) + 4 * hh;
        if (atom < NP) h_lds[atom * 64 + ch] += acc[q] + bias;
      }
    } else {
      int ci = tid - 128;
      if (ci < NP * 3) {
        int p = ci / 3, c = ci - 3 * p;
        cbuf[p * 4 + c] += cupd[p * 4 + c];
      }
    }
    __syncthreads();
  }

  // ---- output: vel = coord - coord0 (re-read x), mean-removed
  if (tid < NP * 3) {
    int p = tid / 3, c = tid - p * 3;
    cupd[p * 4 + c] = cbuf[p * 4 + c] - x[b * (NP * 3) + tid];
  }
  __syncthreads();
  if (tid < 3) {
    float s = 0.f;
    for (int p = 0; p < NP; ++p) s += cupd[p * 4 + tid];
    velm[tid] = s * (1.0f / 22.0f);
  }
  __syncthreads();
  if (tid < NP * 3) {
    int p = tid / 3, c = tid - p * 3;
    out[b * (NP * 3) + tid] = cupd[p * 4 + c] - velm[c];
  }
}

extern "C" void kernel_launch(void* const* d_in, const int* in_sizes, int n_in,
                              void* d_out, int out_size, void* d_ws, size_t ws_size,
                              hipStream_t stream) {
  const float* t    = (const float*)d_in[0];
  const float* x    = (const float*)d_in[1];
  const float* embW = (const float*)d_in[2];
  const float* embB = (const float*)d_in[3];
  // d_in[4] out_W, d_in[5] out_b: do not affect the returned velocities
  const float* ew1  = (const float*)d_in[6];
  const float* eb1  = (const float*)d_in[7];
  const float* ew2  = (const float*)d_in[8];
  const float* eb2  = (const float*)d_in[9];
  const float* nw1  = (const float*)d_in[10];
  const float* nb1  = (const float*)d_in[11];
  const float* nw2  = (const float*)d_in[12];
  const float* nb2  = (const float*)d_in[13];
  const float* cw1  = (const float*)d_in[14];
  const float* cb1  = (const float*)d_in[15];
  const float* cw2  = (const float*)d_in[16];
  const float* aw   = (const float*)d_in[17];
  const float* ab   = (const float*)d_in[18];
  // d_in[19] rows, d_in[20] cols: edge list regenerated analytically in-kernel

  egnn_kernel<<<1024, 256, 0, stream>>>(t, x, embW, embB, ew1, eb1, ew2, eb2,
                                        nw1, nb1, nw2, nb2, cw1, cb1, cw2,
                                        aw, ab, (float*)d_out);
}

// Round 9
// 458.040 us; speedup vs baseline: 1.9277x; 1.0316x over previous
//
#include <hip/hip_runtime.h>

#define NP 22
#define NH 64
#define NL 5
#define NE 21

constexpr float CRc    = 3.0f;   // 15/L
constexpr float LOG2Mc = 7.0f;
constexpr float L2E    = 1.442695041f;

typedef __fp16 h2_t  __attribute__((ext_vector_type(2)));
typedef __fp16 f16x8 __attribute__((ext_vector_type(8)));
typedef float  f32x16 __attribute__((ext_vector_type(16)));

// ---- native single-instruction transcendentals
__device__ __forceinline__ float rcp_(float x) {
#if __has_builtin(__builtin_amdgcn_rcpf)
  return __builtin_amdgcn_rcpf(x);
#else
  float r; asm("v_rcp_f32 %0, %1" : "=v"(r) : "v"(x)); return r;
#endif
}
__device__ __forceinline__ float exp2_(float x) {
#if __has_builtin(__builtin_amdgcn_exp2f)
  return __builtin_amdgcn_exp2f(x);
#else
  float r; asm("v_exp_f32 %0, %1" : "=v"(r) : "v"(x)); return r;
#endif
}
__device__ __forceinline__ float sqrt_(float x) {
#if __has_builtin(__builtin_amdgcn_sqrtf)
  return __builtin_amdgcn_sqrtf(x);
#else
  float r; asm("v_sqrt_f32 %0, %1" : "=v"(r) : "v"(x)); return r;
#endif
}
__device__ __forceinline__ float sigf(float s)  { return rcp_(1.0f + exp2_(-L2E * s)); }
__device__ __forceinline__ float siluf(float s) { return s * sigf(s); }

__device__ __forceinline__ float rl_f(float v, int lane) {
  return __builtin_bit_cast(float, __builtin_amdgcn_readlane(__builtin_bit_cast(int, v), lane));
}
__device__ __forceinline__ h2_t rl_h2(h2_t v, int lane) {
  return __builtin_bit_cast(h2_t, __builtin_amdgcn_readlane(__builtin_bit_cast(int, v), lane));
}
__device__ __forceinline__ h2_t pkf(float a, float b) {
  return __builtin_amdgcn_cvt_pkrtz(a, b);
}
template <int CTRL>
__device__ __forceinline__ float dppmov(float v) {
  return __builtin_bit_cast(float,
      __builtin_amdgcn_update_dpp(0, __builtin_bit_cast(int, v), CTRL, 0xF, 0xF, true));
}
// sum over each 32-lane group
__device__ __forceinline__ float red32(float v) {
  v += dppmov<0xB1>(v);
  v += dppmov<0x4E>(v);
  v += dppmov<0x124>(v);
  v += dppmov<0x128>(v);
  v += __builtin_bit_cast(float, __builtin_amdgcn_ds_swizzle(
         __builtin_bit_cast(int, v), 0x401F));
  return v;
}
__device__ __forceinline__ float fdot2(h2_t a, h2_t b, float c) {
#if __has_builtin(__builtin_amdgcn_fdot2)
  return __builtin_amdgcn_fdot2(a, b, c, false);
#else
  float d;
  asm("v_dot2_f32_f16 %0, %1, %2, %3"
      : "=v"(d)
      : "v"(__builtin_bit_cast(int, a)), "v"(__builtin_bit_cast(int, b)), "v"(c));
  return d;
#endif
}

// LDS arena offsets (bytes)
#define OFF_WLDS   0        // 24576  B-fragment blocks (24 x 1KB)
#define OFF_AMG    24576    // 10880  85 rows x 32 words (4 waves x 21 rows + dump row 84)
#define OFF_HLDS   35456    // 5632   fp32 master h [22][64]
#define OFF_HIBUF  41088    // 5632   hi_part f32 / ubuf
#define OFF_HCBUF  46720    // 5632   hc_part f32
#define OFF_AGGU   52352    // 2816   agg f16 A-tile, then u16 A-tile
#define OFF_EAS    55168    // 1848   initial sq dists f32[462]
#define OFF_CBUF   57024    // 352    coords [22][4]
#define OFF_CUPD   57376    // 352    coord updates (vels at end)
#define OFF_VELM   57728    // 16
#define LDS_BYTES  57744

__global__ __launch_bounds__(256, 2) void egnn_kernel(
    const float* __restrict__ t,   const float* __restrict__ x,
    const float* __restrict__ embW, const float* __restrict__ embB,
    const float* __restrict__ ew1, const float* __restrict__ eb1,
    const float* __restrict__ ew2, const float* __restrict__ eb2,
    const float* __restrict__ nw1, const float* __restrict__ nb1,
    const float* __restrict__ nw2, const float* __restrict__ nb2,
    const float* __restrict__ cw1, const float* __restrict__ cb1,
    const float* __restrict__ cw2, const float* __restrict__ aw,
    const float* __restrict__ ab,  float* __restrict__ out)
{
  __shared__ __align__(16) char LDSRAW[LDS_BYTES];
  int*   wlds  = (int*)(LDSRAW + OFF_WLDS);
  int*   amg   = (int*)(LDSRAW + OFF_AMG);
  float* h_lds = (float*)(LDSRAW + OFF_HLDS);
  float* hibuf = (float*)(LDSRAW + OFF_HIBUF);
  float* hcbuf = (float*)(LDSRAW + OFF_HCBUF);
  int*   aggu  = (int*)(LDSRAW + OFF_AGGU);
  float* eas   = (float*)(LDSRAW + OFF_EAS);
  float* cbuf  = (float*)(LDSRAW + OFF_CBUF);
  float* cupd  = (float*)(LDSRAW + OFF_CUPD);
  float* velm  = (float*)(LDSRAW + OFF_VELM);

  const int b = blockIdx.x, tid = threadIdx.x;
  const int lane = tid & 63, wv = tid >> 6;
  const int c31 = lane & 31, hh = lane >> 5;
  const int xorv = ((lane >> 3) & 7) << 2;   // B swizzle

  // blocks [0,8)->m0, [8,16)->m1, [16,24)->m2 (each matrix = 64 rows = 8 blocks)
  auto fillblk3 = [&](const float* m0, const float* m1, const float* m2, int nblocks) {
    for (int blk = wv; blk < nblocks; blk += 4) {
      const float* Ws = (blk < 8) ? m0 : ((blk < 16) ? m1 : m2);
      int kb = (blk >> 1) & 3, n = blk & 1;
      int k0 = kb * 16 + hh * 8;
      int ch = n * 32 + c31;
      int wb = blk * 256 + ((lane * 4) ^ xorv);
#pragma unroll
      for (int w = 0; w < 4; ++w) {
        h2_t p = pkf(Ws[(k0 + 2 * w) * NH + ch], Ws[(k0 + 2 * w + 1) * NH + ch]);
        wlds[wb + w] = __builtin_bit_cast(int, p);
      }
    }
  };
  auto bread = [&](int blk) -> f16x8 {
    return __builtin_bit_cast(f16x8, *(const int4*)&wlds[blk * 256 + ((lane * 4) ^ xorv)]);
  };
  auto aread = [&](const int* tile, int ks) -> f16x8 {
    int off = (ks * 8 + hh * 4) ^ ((c31 & 7) << 2);
    return __builtin_bit_cast(f16x8, *(const int4*)&tile[c31 * 32 + off]);
  };
  auto packh = [&]() {
    for (int idx = tid; idx < NP * 32; idx += 256) {
      int atom = idx >> 5, w = idx & 31;
      h2_t p = pkf(h_lds[atom * 64 + 2 * w], h_lds[atom * 64 + 2 * w + 1]);
      amg[atom * 32 + (w ^ ((atom & 7) << 2))] = __builtin_bit_cast(int, p);
    }
  };

  // ---- init
  if (tid < NP * 3) {
    int p = tid / 3, c = tid - p * 3;
    cbuf[p * 4 + c] = x[b * (NP * 3) + tid];
  }
  float tb = t[b];
  for (int p = wv; p < NP; p += 4)
    h_lds[p * 64 + lane] = embW[p * NH + lane] + tb * embW[22 * NH + lane]
                         + LOG2Mc * embW[23 * NH + lane] + embB[lane];
  __syncthreads();
  for (int idx = tid; idx < NP * NE; idx += 256) {
    int r = idx / NE, e = idx - r * NE, col = e + (e >= r);
    float dx = cbuf[r * 4 + 0] - cbuf[col * 4 + 0];
    float dy = cbuf[r * 4 + 1] - cbuf[col * 4 + 1];
    float dz = cbuf[r * 4 + 2] - cbuf[col * 4 + 2];
    eas[idx] = dx * dx + dy * dy + dz * dz;
  }
  __syncthreads();

  for (int l = 0; l < NL; ++l) {
    const float* W1 = ew1 + l * 130 * NH;
    const float* W2 = ew2 + l * NH * NH;
    const float* C1 = cw1 + l * NH * NH;
    const float* N1 = nw1 + l * 128 * NH;
    const float* N2 = nw2 + l * NH * NH;

    // ---- step1: wlds <- W1lo(0-7), W1hi(8-15), W2(16-23); pack h A-tile
    fillblk3(W1, W1 + 64 * NH, W2, 24);
    packh();
    __syncthreads();

    // ---- step2: phase0 — hi (waves 0,1) / hc (waves 2,3)
    {
      int s = wv >> 1, n = wv & 1;
      f32x16 acc;
#pragma unroll
      for (int i = 0; i < 16; ++i) acc[i] = 0.f;
#pragma unroll
      for (int ks = 0; ks < 4; ++ks)
        acc = __builtin_amdgcn_mfma_f32_32x32x16_f16(aread(amg, ks),
                bread((s * 4 + ks) * 2 + n), acc, 0, 0, 0);
      int ch = n * 32 + c31;
      float bias = (s == 0) ? eb1[l * NH + ch] : 0.0f;
      float* dst = (s == 0) ? hibuf : hcbuf;
#pragma unroll
      for (int q = 0; q < 16; ++q) {
        int atom = (q & 3) + 8 * (q >> 2) + 4 * hh;
        if (atom < NP) dst[atom * 64 + ch] = acc[q] + bias;
      }
    }
    __syncthreads();

    // ---- step3: wlds blocks 0-7 <- C1 (over W1lo; W2 in 16-23 survives)
    fillblk3(C1, C1, C1, 8);
    __syncthreads();

    // ---- step4: edge phase
    float w128r = W1[128 * NH + lane], w129r = W1[129 * NH + lane];
    float b2r0 = eb2[l * NH + c31],  b2r1 = eb2[l * NH + 32 + c31];
    float abl  = ab[l];
    float cb1r0 = cb1[l * NH + c31], cb1r1 = cb1[l * NH + 32 + c31];
    h2_t  awT  = pkf(aw[l * NH + 2 * c31],  aw[l * NH + 2 * c31 + 1]);
    h2_t  c2T  = pkf(cw2[l * NH + 2 * c31], cw2[l * NH + 2 * c31 + 1]);

    const int abase = wv * (NE * 32);
    for (int r = wv; r < NP; r += 4) {
      // per-lane edge geometry (lane = edge index) — stays in registers
      int eL = (lane < NE) ? lane : NE - 1;
      int colL = eL + (eL >= r);
      float4 ccL = *(const float4*)&cbuf[colL * 4];
      float4 crL = *(const float4*)&cbuf[r * 4];
      float gdx = crL.x - ccL.x, gdy = crL.y - ccL.y, gdz = crL.z - ccL.z;
      float radialT = gdx * gdx + gdy * gdy + gdz * gdz;
      float ndT = rcp_(sqrt_(radialT) + 1.0f);
      float eaT = eas[r * NE + eL];
      float hii = hibuf[r * 64 + lane];

      // phase1: m1 for 21 edges, staged full-rate in pairs
#pragma unroll
      for (int e2 = 0; e2 < 20; e2 += 2) {
        int ea_ = e2, eb_ = e2 + 1;
        int cola = ea_ + (ea_ >= r), colb = eb_ + (eb_ >= r);
        float ra = rl_f(radialT, ea_), rb = rl_f(radialT, eb_);
        float qa = rl_f(eaT, ea_),     qb = rl_f(eaT, eb_);
        float s1a = hii + hcbuf[cola * 64 + lane];
        s1a = fmaf(ra, w128r, s1a); s1a = fmaf(qa, w129r, s1a);
        float s1b = hii + hcbuf[colb * 64 + lane];
        s1b = fmaf(rb, w128r, s1b); s1b = fmaf(qb, w129r, s1b);
        float m1a = siluf(s1a), m1b = siluf(s1b);
        h2_t wa = pkf(m1a, dppmov<0xB1>(m1a));   // valid even lanes
        h2_t wb = pkf(dppmov<0xB1>(m1b), m1b);   // valid odd lanes
        int row = (lane & 1) ? eb_ : ea_;
        int w = lane >> 1;
        amg[abase + row * 32 + (w ^ ((row & 7) << 2))] =
            (lane & 1) ? __builtin_bit_cast(int, wb) : __builtin_bit_cast(int, wa);
      }
      { // tail edge 20
        int col20 = 20 + (20 >= r);
        float ra = rl_f(radialT, 20), qa = rl_f(eaT, 20);
        float s1 = hii + hcbuf[col20 * 64 + lane];
        s1 = fmaf(ra, w128r, s1); s1 = fmaf(qa, w129r, s1);
        float m1 = siluf(s1);
        h2_t wa = pkf(m1, dppmov<0xB1>(m1));
        if (!(lane & 1))
          amg[abase + 20 * 32 + ((lane >> 1) ^ ((20 & 7) << 2))] = __builtin_bit_cast(int, wa);
      }

      // pass1: m1 @ W2 (blocks 16-23)
      f32x16 acc0, acc1;
#pragma unroll
      for (int i = 0; i < 16; ++i) { acc0[i] = 0.f; acc1[i] = 0.f; }
#pragma unroll
      for (int ks = 0; ks < 4; ++ks) {
        f16x8 af = aread(&amg[abase], ks);
        acc0 = __builtin_amdgcn_mfma_f32_32x32x16_f16(af, bread(16 + ks * 2 + 0), acc0, 0, 0, 0);
        acc1 = __builtin_amdgcn_mfma_f32_32x32x16_f16(af, bread(16 + ks * 2 + 1), acc1, 0, 0, 0);
      }

      // post1: m2 = silu(s2 + b2); restage m2; invalid rows -> dump row 84
#pragma unroll
      for (int q = 0; q < 16; ++q) {
        int e0 = (q & 3) + 8 * (q >> 2);     // e0 in {0..3,8..11,16..19,24..27}
        int rowq = e0 + 4 * hh;
        float m20 = siluf(acc0[q] + b2r0);
        float m21 = siluf(acc1[q] + b2r1);
        acc0[q] = m20; acc1[q] = m21;
        h2_t w0 = pkf(m20, dppmov<0xB1>(m20));   // even lanes
        h2_t w1 = pkf(dppmov<0xB1>(m21), m21);   // odd lanes
        int wq = (lane & 1) ? 16 + (c31 >> 1) : (c31 >> 1);
        int adr = (rowq < NE) ? (abase + rowq * 32 + (wq ^ ((rowq & 7) << 2)))
                              : (84 * 32 + wq);
        amg[adr] = (lane & 1) ? __builtin_bit_cast(int, w1) : __builtin_bit_cast(int, w0);
      }

      // gate: lane = edge, 64-ch dot over staged m2 tile
      float gg = 0.f;
      {
        int xr = (c31 & 7) << 2;
#pragma unroll
        for (int tt = 0; tt < 8; ++tt) {
          int4 v4 = *(const int4*)&amg[abase + c31 * 32 + ((4 * tt) ^ xr)];
          gg = fdot2(__builtin_bit_cast(h2_t, v4.x), rl_h2(awT, 4 * tt + 0), gg);
          gg = fdot2(__builtin_bit_cast(h2_t, v4.y), rl_h2(awT, 4 * tt + 1), gg);
          gg = fdot2(__builtin_bit_cast(h2_t, v4.z), rl_h2(awT, 4 * tt + 2), gg);
          gg = fdot2(__builtin_bit_cast(h2_t, v4.w), rl_h2(awT, 4 * tt + 3), gg);
        }
      }
      float sgT = sigf(gg + abl);                // valid in lanes 0..20

      // pass2: m2 @ C1 (blocks 0-7)
      f32x16 acc2, acc3;
#pragma unroll
      for (int i = 0; i < 16; ++i) { acc2[i] = 0.f; acc3[i] = 0.f; }
#pragma unroll
      for (int ks = 0; ks < 4; ++ks) {
        f16x8 af = aread(&amg[abase], ks);
        acc2 = __builtin_amdgcn_mfma_f32_32x32x16_f16(af, bread(ks * 2 + 0), acc2, 0, 0, 0);
        acc3 = __builtin_amdgcn_mfma_f32_32x32x16_f16(af, bread(ks * 2 + 1), acc3, 0, 0, 0);
      }

      // post2a (q-domain): agg + c1 = silu(sg*acc + cb1) restaged into tile
      float aggn0 = 0.f, aggn1 = 0.f;
#pragma unroll
      for (int q = 0; q < 16; ++q) {
        int e0 = (q & 3) + 8 * (q >> 2);
        int rowq = e0 + 4 * hh;
        bool valid = (rowq < NE);
        float sg = hh ? rl_f(sgT, e0 + 4) : rl_f(sgT, e0);
        aggn0 += valid ? acc0[q] * sg : 0.f;     // select, not multiply-by-0
        aggn1 += valid ? acc1[q] * sg : 0.f;
        float c10 = siluf(fmaf(sg, acc2[q], cb1r0));
        float c11 = siluf(fmaf(sg, acc3[q], cb1r1));
        h2_t w0 = pkf(c10, dppmov<0xB1>(c10));   // even lanes
        h2_t w1 = pkf(dppmov<0xB1>(c11), c11);   // odd lanes
        int wq = (lane & 1) ? 16 + (c31 >> 1) : (c31 >> 1);
        int adr = valid ? (abase + rowq * 32 + (wq ^ ((rowq & 7) << 2)))
                        : (84 * 32 + wq);
        amg[adr] = (lane & 1) ? __builtin_bit_cast(int, w1) : __builtin_bit_cast(int, w0);
      }
      aggn0 += __shfl_xor(aggn0, 32, 64);
      aggn1 += __shfl_xor(aggn1, 32, 64);
      { // write agg directly as f16 A-tile row r
        h2_t a0p = pkf(aggn0, dppmov<0xB1>(aggn0));   // even lanes
        h2_t a1p = pkf(dppmov<0xB1>(aggn1), aggn1);   // odd lanes
        if (lane < 32) {
          int wq = (lane & 1) ? 16 + (c31 >> 1) : (c31 >> 1);
          aggu[r * 32 + (wq ^ ((r & 7) << 2))] =
              (lane & 1) ? __builtin_bit_cast(int, a1p) : __builtin_bit_cast(int, a0p);
        }
      }

      // post2b (lane=edge): d = c1[e].c2 ; th ; coord contributions ; 3 reductions
      float dd = 0.f;
      {
        int xr = (c31 & 7) << 2;
#pragma unroll
        for (int tt = 0; tt < 8; ++tt) {
          int4 v4 = *(const int4*)&amg[abase + c31 * 32 + ((4 * tt) ^ xr)];
          dd = fdot2(__builtin_bit_cast(h2_t, v4.x), rl_h2(c2T, 4 * tt + 0), dd);
          dd = fdot2(__builtin_bit_cast(h2_t, v4.y), rl_h2(c2T, 4 * tt + 1), dd);
          dd = fdot2(__builtin_bit_cast(h2_t, v4.z), rl_h2(c2T, 4 * tt + 2), dd);
          dd = fdot2(__builtin_bit_cast(h2_t, v4.w), rl_h2(c2T, 4 * tt + 3), dd);
        }
      }
      float th = 1.0f - 2.0f * rcp_(1.0f + exp2_(2.0f * L2E * dd));
      float ff = th * CRc * ndT;
      bool vlane = (lane < NE);                  // lanes 21..63 discarded (NaN-safe select)
      float cxc = vlane ? gdx * ff : 0.f;
      float cyc = vlane ? gdy * ff : 0.f;
      float czc = vlane ? gdz * ff : 0.f;
      cxc = red32(cxc);                          // lower 32-group holds full sum
      cyc = red32(cyc);
      czc = red32(czc);
      if (lane < 3) {
        float cv = (lane == 0) ? cxc : (lane == 1) ? cyc : czc;
        cupd[r * 4 + lane] = cv;
      }
    }
    __syncthreads();

    // ---- step5: wlds <- N1lo(0-7), N1hi(8-15), N2(16-23); repack h A-tile
    fillblk3(N1, N1 + 64 * NH, N2, 24);
    packh();
    __syncthreads();

    // ---- step6: u = h@N1lo + agg@N1hi + nb1 -> hibuf (ubuf), waves 0,1
    if (wv < 2) {
      int n = wv;
      f32x16 acc;
#pragma unroll
      for (int i = 0; i < 16; ++i) acc[i] = 0.f;
#pragma unroll
      for (int ks = 0; ks < 4; ++ks)
        acc = __builtin_amdgcn_mfma_f32_32x32x16_f16(aread(amg, ks),
                bread(ks * 2 + n), acc, 0, 0, 0);
#pragma unroll
      for (int ks = 0; ks < 4; ++ks)
        acc = __builtin_amdgcn_mfma_f32_32x32x16_f16(aread(aggu, ks),
                bread((4 + ks) * 2 + n), acc, 0, 0, 0);
      float bias = nb1[l * NH + n * 32 + c31];
#pragma unroll
      for (int q = 0; q < 16; ++q) {
        int atom = (q & 3) + 8 * (q >> 2) + 4 * hh;
        if (atom < NP) hibuf[atom * 64 + n * 32 + c31] = acc[q] + bias;
      }
    }
    __syncthreads();

    // ---- step7: u16 tile over aggu from silu(ubuf) (all threads)
    for (int idx = tid; idx < NP * 32; idx += 256) {
      int atom = idx >> 5, w = idx & 31;
      h2_t p = pkf(siluf(hibuf[atom * 64 + 2 * w]), siluf(hibuf[atom * 64 + 2 * w + 1]));
      aggu[atom * 32 + (w ^ ((atom & 7) << 2))] = __builtin_bit_cast(int, p);
    }
    __syncthreads();

    // ---- step8: h += u16@N2 + nb2 (waves 0,1); coords += cupd (waves 2,3)
    if (wv < 2) {
      int n = wv;
      f32x16 acc;
#pragma unroll
      for (int i = 0; i < 16; ++i) acc[i] = 0.f;
#pragma unroll
      for (int ks = 0; ks < 4; ++ks)
        acc = __builtin_amdgcn_mfma_f32_32x32x16_f16(aread(aggu, ks),
                bread(16 + ks * 2 + n), acc, 0, 0, 0);
      int ch = n * 32 + c31;
      float bias = nb2[l * NH + ch];
#pragma unroll
      for (int q = 0; q < 16; ++q) {
        int atom = (q & 3) + 8 * (q >> 2) + 4 * hh;
        if (atom < NP) h_lds[atom * 64 + ch] += acc[q] + bias;
      }
    } else {
      int ci = tid - 128;
      if (ci < NP * 3) {
        int p = ci / 3, c = ci - 3 * p;
        cbuf[p * 4 + c] += cupd[p * 4 + c];
      }
    }
    __syncthreads();
  }

  // ---- output: vel = coord - coord0 (re-read x), mean-removed
  if (tid < NP * 3) {
    int p = tid / 3, c = tid - p * 3;
    cupd[p * 4 + c] = cbuf[p * 4 + c] - x[b * (NP * 3) + tid];
  }
  __syncthreads();
  if (tid < 3) {
    float s = 0.f;
    for (int p = 0; p < NP; ++p) s += cupd[p * 4 + tid];
    velm[tid] = s * (1.0f / 22.0f);
  }
  __syncthreads();
  if (tid < NP * 3) {
    int p = tid / 3, c = tid - p * 3;
    out[b * (NP * 3) + tid] = cupd[p * 4 + c] - velm[c];
  }
}

extern "C" void kernel_launch(void* const* d_in, const int* in_sizes, int n_in,
                              void* d_out, int out_size, void* d_ws, size_t ws_size,
                              hipStream_t stream) {
  const float* t    = (const float*)d_in[0];
  const float* x    = (const float*)d_in[1];
  const float* embW = (const float*)d_in[2];
  const float* embB = (const float*)d_in[3];
  // d_in[4] out_W, d_in[5] out_b: do not affect the returned velocities
  const float* ew1  = (const float*)d_in[6];
  const float* eb1  = (const float*)d_in[7];
  const float* ew2  = (const float*)d_in[8];
  const float* eb2  = (const float*)d_in[9];
  const float* nw1  = (const float*)d_in[10];
  const float* nb1  = (const float*)d_in[11];
  const float* nw2  = (const float*)d_in[12];
  const float* nb2  = (const float*)d_in[13];
  const float* cw1  = (const float*)d_in[14];
  const float* cb1  = (const float*)d_in[15];
  const float* cw2  = (const float*)d_in[16];
  const float* aw   = (const float*)d_in[17];
  const float* ab   = (const float*)d_in[18];
  // d_in[19] rows, d_in[20] cols: edge list regenerated analytically in-kernel

  egnn_kernel<<<1024, 256, 0, stream>>>(t, x, embW, embB, ew1, eb1, ew2, eb2,
                                        nw1, nb1, nw2, nb2, cw1, cb1, cw2,
                                        aw, ab, (float*)d_out);
}